// Round 11
// baseline (203.708 us; speedup 1.0000x reference)
//
#include <hip/hip_runtime.h>
#include <math.h>

#define NN 500
#define NE 64
#define BATCH 8
#define RR 15
#define PW 31            // 2R+1
#define CAN 200
#define OHW 198
#define TWO_PI_F 6.28318530717958647692f
// k_setup covers canvas (320000) + psf_sums (64) + kern (49).
#define SETUP_N (BATCH * CAN * CAN + NE + 49)

// Fast accurate sincos for |theta| up to ~1200 rad: Cody-Waite 2-term
// reduction + hardware v_sin/v_cos on the reduced |r| <= pi argument.
__device__ __forceinline__ void fast_sincos_red(float theta, float* s, float* c) {
    const float INV2PI = 0.15915494309189535f;
    const float PI2_HI = 6.28318548202514648f;   // f32(2*pi)
    const float PI2_LO = -1.7484556e-7f;         // 2*pi - PI2_HI
    float n = rintf(theta * INV2PI);
    float r = fmaf(n, -PI2_HI, theta);
    r = fmaf(n, -PI2_LO, r);
    *s = __sinf(r);
    *c = __cosf(r);
}

// ---------------------------------------------------------------------------
// K_setup: 500-pt twiddle table, blur-kernel coefficients, canvas+psf_sums
// zero. (kgamma now computed inline in k_prop_rows; field gen in k_dft_rows.)
// ---------------------------------------------------------------------------
__global__ void k_setup(const float* __restrict__ std_u,
                        float2* __restrict__ tw,
                        float* __restrict__ kern,
                        float* __restrict__ canvas,
                        float* __restrict__ psf_sums) {
    int idx = blockIdx.x * blockDim.x + threadIdx.x;
    if (idx < NN) {
        double th = 2.0 * M_PI * (double)idx / (double)NN;
        tw[idx] = make_float2((float)cos(th), (float)sin(th));
    }
    if (idx < BATCH * CAN * CAN) canvas[idx] = 0.f;
    if (idx >= BATCH * CAN * CAN && idx < BATCH * CAN * CAN + NE)
        psf_sums[idx - BATCH * CAN * CAN] = 0.f;
    if (idx >= BATCH * CAN * CAN + NE && idx < SETUP_N) {
        int t = idx - (BATCH * CAN * CAN + NE);
        float stdv = 0.8f + 0.4f * std_u[0];
        float s2 = stdv * stdv;
        int a = t / 7 - 3, b = t % 7 - 3;
        float g = (float)exp(-0.5 * (double)(a * a + b * b));
        kern[t] = (1.0f / (2.0f * (float)M_PI * s2)) * powf(g, 1.0f / s2);
    }
}

// ---------------------------------------------------------------------------
// 500-pt forward DFT via Cooley-Tukey 20x25. Shared stages helper.
// ---------------------------------------------------------------------------
__device__ __forceinline__ void ct_dft_stages(const float2* xs, const float2* tts,
                                              float2* S, int t,
                                              float2* out1, float2* out2, int* kout) {
    if (t < 250) {
        int d = t / 25;
        int b = t % 25;
        float2 st = tts[(25 * d) % NN];
        float wr = 1.f, wi = 0.f;
        float Er = 0.f, Ei = 0.f, Or_ = 0.f, Oi = 0.f;
#pragma unroll
        for (int a = 0; a < 20; a += 2) {
            float2 x0 = xs[25 * a + b];
            Er += x0.x * wr - x0.y * wi;
            Ei += x0.x * wi + x0.y * wr;
            float nr = wr * st.x - wi * st.y;
            float ni = wr * st.y + wi * st.x;
            float2 x1 = xs[25 * (a + 1) + b];
            Or_ += x1.x * nr - x1.y * ni;
            Oi  += x1.x * ni + x1.y * nr;
            wr = nr * st.x - ni * st.y;
            wi = nr * st.y + ni * st.x;
        }
        S[b * 21 + d]      = make_float2(Er + Or_, Ei + Oi);
        S[b * 21 + d + 10] = make_float2(Er - Or_, Ei - Oi);
    }
    __syncthreads();
    if (t < 250) {
        int k = t;
        int d1 = k % 20;
        int d2 = (d1 + 10) % 20;
        float2 s1 = tts[k];
        float wr = 1.f, wi = 0.f;
        float a1r = 0.f, a1i = 0.f, a2r = 0.f, a2i = 0.f;
#pragma unroll
        for (int b = 0; b < 25; ++b) {
            float2 u1 = S[b * 21 + d1];
            float2 u2 = S[b * 21 + d2];
            a1r += u1.x * wr - u1.y * wi;
            a1i += u1.x * wi + u1.y * wr;
            float sgnb = (b & 1) ? -1.f : 1.f;
            float w2r = sgnb * wr, w2i = sgnb * wi;
            a2r += u2.x * w2r - u2.y * w2i;
            a2i += u2.x * w2i + u2.y * w2r;
            float nr = wr * s1.x - wi * s1.y;
            wi = wr * s1.y + wi * s1.x;
            wr = nr;
        }
        *out1 = make_float2(a1r, a1i);
        *out2 = make_float2(a2r, a2i);
        *kout = k;
    }
}

// k_dft_rows: fused pupil-field generation (f32) + row DFT; writes R1T[k][y].
__global__ void k_dft_rows(const float* __restrict__ phase, float2* __restrict__ dst,
                           const float2* __restrict__ tw) {
    __shared__ __align__(16) float2 xs[NN];
    __shared__ float2 tts[NN];
    __shared__ float2 S[25 * 21];
    int line = blockIdx.x;                 // y index i
    int t = threadIdx.x;
    const float INV2SIG = 2.2222222e7f;              // 1/(2*(1.5e-4)^2)
    const float C1M = (float)(M_PI / 5.32e-8);       // pi/(WL*FL)
    float y = (float)(line - 250) * 1e-6f;
    float y2 = y * y;
    const float* prow = phase + (size_t)line * NN;
    for (int n = t; n < NN; n += 256) {
        float x = (float)(n - 250) * 1e-6f;
        float r2 = x * x + y2;
        float inc = __expf(-r2 * INV2SIG);
        float c1 = C1M * r2;
        float b1r = __cosf(c1), b1i = -__sinf(c1);
        float ph = prow[n];
        float sp = __sinf(ph), cp = __cosf(ph);
        float ar = inc * cp, ai = inc * sp;
        xs[n] = make_float2(ar * b1r - ai * b1i, ar * b1i + ai * b1r);
        float2 tt = tw[n];
        tts[n] = make_float2(tt.x, -tt.y);   // forward
    }
    __syncthreads();
    float2 o1, o2; int k;
    ct_dft_stages(xs, tts, S, t, &o1, &o2, &k);
    if (t < 250) {
        dst[(size_t)k * NN + line] = o1;           // R1T[k][y]
        dst[(size_t)(k + 250) * NN + line] = o2;
    }
}

__global__ void k_dft_cols(const float2* __restrict__ src, float2* __restrict__ dst,
                           const float2* __restrict__ tw) {
    __shared__ __align__(16) float2 xs[NN];
    __shared__ float2 tts[NN];
    __shared__ float2 S[25 * 21];
    int line = blockIdx.x;                 // kx
    const float2* s = src + (size_t)line * NN;     // R1T row kx, contiguous
    int t = threadIdx.x;
    for (int n = t; n < NN; n += 256) {
        xs[n] = s[n];
        float2 tt = tw[n];
        tts[n] = make_float2(tt.x, -tt.y);
    }
    __syncthreads();
    float2 o1, o2; int k;
    ct_dft_stages(xs, tts, S, t, &o1, &o2, &k);
    if (t < 250) {
        float2* dp = dst + (size_t)line * NN;      // EfT[kx][*], contiguous
        dp[k] = o1;
        dp[k + 250] = o2;
    }
}

// ---------------------------------------------------------------------------
// B1 v11: grid (v, zq in [0,4)) -> 2000 blocks, 2 passes of 8 z each
// (5 blocks/CU LDS-capped packing vs 3.9 all-resident at (NN,2)).
// kgamma computed INLINE (exact f64 formula — no global read); rotator init
// via hw __sinf/__cosf (args < 2pi); EfT row prefetched to registers.
//   part[z][r][v] = sum_u EfT[v,u]*e^{i*kg[v,u]*z} * e^{+2pi*i*u*r/500}
// ---------------------------------------------------------------------------
__global__ void __launch_bounds__(256, 5)
k_prop_rows(const float2* __restrict__ EfT,
            const float* __restrict__ zs,
            float2* __restrict__ part) {
    __shared__ __align__(16) float4 Yeo[8][250];   // 32000 B
    int v = blockIdx.x;
    int zq = blockIdx.y;        // 0..3
    int t = threadIdx.x;
    int w = t >> 6;             // wave id 0..3 -> z rows 2w, 2w+1
    int lane = t & 63;
    int co = lane >> 3;         // 0..7 : r-quad index
    int vs = lane & 7;          // 0..7 : u-segment
    int r0 = 235 + 4 * co;      // r = r0..r0+3 (co=7,rl=3 -> 266 dummy)

    const float2* erow = EfT + (size_t)v * NN;

    // prefetch EfT row pair + inline kgamma (f64, identical op sequence to
    // the reference: a from u/column, b from v/row)
    float2 eA = make_float2(0.f, 0.f), eB = eA;
    float kgA = 0.f, kgB = 0.f;
    if (t < 250) {
        eA = erow[t];   eB = erow[t + 250];
        double fyv = (double)((v < 250) ? v : v - 500) * 2000.0;
        double b = 5.32e-7 * fyv;
        double aA = 5.32e-7 * ((double)t * 2000.0);          // u = t < 250
        double aB = 5.32e-7 * ((double)(t - 250) * 2000.0);  // u = t+250 -> u-500
        double gA = 1.0 - aA * aA - b * b;
        double gB = 1.0 - aB * aB - b * b;
        gA = (gA > 0.0) ? sqrt(gA) : 0.0;
        gB = (gB > 0.0) ? sqrt(gB) : 0.0;
        const float Kf = (float)(2.0 * M_PI * 1.0 / 5.32e-7);
        kgA = Kf * (float)gA;
        kgB = Kf * (float)gB;
    }

    // rotator init via hw sincos (args in [0, 2pi), ~1e-6 — inside budget)
    float w0r[4], w0i[4], s1r[4], s1i[4], str[4], sti[4];
#pragma unroll
    for (int rl = 0; rl < 4; ++rl) {
        int r = r0 + rl;
        float th0 = (TWO_PI_F / NN) * (float)((2 * vs * r) % NN);
        w0i[rl] = __sinf(th0);  w0r[rl] = __cosf(th0);
        float th1 = (TWO_PI_F / NN) * (float)(r % NN);
        s1i[rl] = __sinf(th1);  s1r[rl] = __cosf(th1);
        float ths = (TWO_PI_F / NN) * (float)((16 * r) % NN);
        sti[rl] = __sinf(ths);  str[rl] = __cosf(ths);
    }

    for (int g = 0; g < 2; ++g) {
        int zbase = zq * 16 + g * 8;
        float zv[8];
#pragma unroll
        for (int zi = 0; zi < 8; ++zi) zv[zi] = zs[zbase + zi];
        // modulate + parity fold, all from registers
        if (t < 250) {
#pragma unroll
            for (int zi = 0; zi < 8; ++zi) {
                float sA, cA, sB, cB;
                fast_sincos_red(kgA * zv[zi], &sA, &cA);
                fast_sincos_red(kgB * zv[zi], &sB, &cB);
                float y0r = eA.x * cA - eA.y * sA, y0i = eA.x * sA + eA.y * cA;
                float y1r = eB.x * cB - eB.y * sB, y1i = eB.x * sB + eB.y * cB;
                Yeo[zi][t] = make_float4(y0r + y1r, y0i + y1i,
                                         y0r - y1r, y0i - y1i);
            }
        }
        __syncthreads();

        float wr[4], wi[4];
#pragma unroll
        for (int rl = 0; rl < 4; ++rl) { wr[rl] = w0r[rl]; wi[rl] = w0i[rl]; }
        float accr[4][2], acci[4][2];
#pragma unroll
        for (int rl = 0; rl < 4; ++rl)
#pragma unroll
            for (int j = 0; j < 2; ++j) { accr[rl][j] = 0.f; acci[rl][j] = 0.f; }

        for (int pc = vs; pc < 125; pc += 8) {   // columns u=2pc, 2pc+1
            int u = 2 * pc;
            float4 y0a = Yeo[2 * w + 0][u];      // z row 0: col u  {e,o}
            float4 y0b = Yeo[2 * w + 0][u + 1];  // z row 0: col u+1
            float4 y1a = Yeo[2 * w + 1][u];
            float4 y1b = Yeo[2 * w + 1][u + 1];
#pragma unroll
            for (int rl = 0; rl < 4; ++rl) {
                float ar = wr[rl], ai = wi[rl];              // twiddle at u
                float br = ar * s1r[rl] - ai * s1i[rl];      // twiddle at u+1
                float bi = ar * s1i[rl] + ai * s1r[rl];
                if ((rl & 1) == 0) {   // r odd -> odd-parity (.z,.w)
                    accr[rl][0] += y0a.z * ar - y0a.w * ai + y0b.z * br - y0b.w * bi;
                    acci[rl][0] += y0a.z * ai + y0a.w * ar + y0b.z * bi + y0b.w * br;
                    accr[rl][1] += y1a.z * ar - y1a.w * ai + y1b.z * br - y1b.w * bi;
                    acci[rl][1] += y1a.z * ai + y1a.w * ar + y1b.z * bi + y1b.w * br;
                } else {               // r even -> even-parity (.x,.y)
                    accr[rl][0] += y0a.x * ar - y0a.y * ai + y0b.x * br - y0b.y * bi;
                    acci[rl][0] += y0a.x * ai + y0a.y * ar + y0b.x * bi + y0b.y * br;
                    accr[rl][1] += y1a.x * ar - y1a.y * ai + y1b.x * br - y1b.y * bi;
                    acci[rl][1] += y1a.x * ai + y1a.y * ar + y1b.x * bi + y1b.y * br;
                }
                float nwr = ar * str[rl] - ai * sti[rl];
                wi[rl] = ar * sti[rl] + ai * str[rl];
                wr[rl] = nwr;
            }
        }

#pragma unroll
        for (int rl = 0; rl < 4; ++rl)
#pragma unroll
            for (int j = 0; j < 2; ++j) {
#pragma unroll
                for (int m = 1; m < 8; m <<= 1) {
                    accr[rl][j] += __shfl_xor(accr[rl][j], m);
                    acci[rl][j] += __shfl_xor(acci[rl][j], m);
                }
            }
        if (vs == 0) {
#pragma unroll
            for (int rl = 0; rl < 4; ++rl) {
                int r = r0 + rl;
                if (r <= 265) {
#pragma unroll
                    for (int j = 0; j < 2; ++j) {
                        int z = zbase + 2 * w + j;
                        part[((size_t)z * PW + (r - 235)) * NN + v] =
                            make_float2(accr[rl][j], acci[rl][j]);
                    }
                }
            }
        }
        __syncthreads();
    }
}

// ---------------------------------------------------------------------------
// B2 v2: parity fold halves the inner loop:
//   sum_v X[v] W^{vc} = sum_{v<250} (X[v] + (-1)^c X[v+250]) W^{vc}
// ---------------------------------------------------------------------------
__global__ void k_prop_cols(const float2* __restrict__ part,
                            float* __restrict__ psf,
                            float* __restrict__ psf_sums) {
    __shared__ float2 X[NN];
    __shared__ float sred[PW];
    int r = blockIdx.x;    // 31
    int z = blockIdx.y;    // 64
    int t = threadIdx.x;
    const float2* col = part + ((size_t)z * PW + r) * NN;
    for (int v = t; v < NN; v += 256) X[v] = col[v];
    __syncthreads();
    if (t < PW * 8) {
        int ci = t >> 3, seg = t & 7;
        int c = 235 + ci;
        float sign = (c & 1) ? -1.f : 1.f;     // W^{250c} = (-1)^c
        float wr, wi, sr, si;
        {
            float th0 = (TWO_PI_F / NN) * (float)((seg * c) % NN);
            sincosf(th0, &wi, &wr);
            float ths = (TWO_PI_F / NN) * (float)((8 * c) % NN);
            sincosf(ths, &si, &sr);
        }
        float ar = 0.f, ai = 0.f;
        for (int v = seg; v < 250; v += 8) {
            float2 xa = X[v];
            float2 xb = X[v + 250];
            float xr = fmaf(sign, xb.x, xa.x);
            float xi = fmaf(sign, xb.y, xa.y);
            ar += xr * wr - xi * wi;
            ai += xr * wi + xi * wr;
            float nwr = wr * sr - wi * si;
            wi = wr * si + wi * sr;
            wr = nwr;
        }
#pragma unroll
        for (int m = 1; m < 8; m <<= 1) {
            ar += __shfl_xor(ar, m);
            ai += __shfl_xor(ai, m);
        }
        if (seg == 0 && ci < PW) {
            const float inv = 1.0f / 250000.0f;
            float re = ar * inv, im = ai * inv;
            float val = re * re + im * im;
            psf[(size_t)z * (PW * PW) + r * PW + ci] = val;
            sred[ci] = val;
        }
    }
    __syncthreads();
    if (t == 0) {
        float s = 0.f;
#pragma unroll
        for (int i = 0; i < PW; ++i) s += sred[i];
        atomicAdd(&psf_sums[z], s);
    }
}

// ---------------------------------------------------------------------------
__global__ void k_scatter(const float* __restrict__ psf,
                          const float* __restrict__ psf_sums,
                          const int* __restrict__ xyz,
                          float* __restrict__ canvas) {
    int e = blockIdx.x;
    int b = blockIdx.y;
    int r0 = xyz[(b * NE + e) * 2 + 0] - RR;
    int c0 = xyz[(b * NE + e) * 2 + 1] - RR;
    float sc = 1.0e6f / (psf_sums[e] + 1e-12f);
    float* cb = canvas + (size_t)b * (CAN * CAN);
    for (int p = threadIdx.x; p < PW * PW; p += blockDim.x) {
        int i = p / PW, j = p % PW;
        atomicAdd(cb + (r0 + i) * CAN + (c0 + j), psf[e * PW * PW + p] * sc);
    }
}

// ---------------------------------------------------------------------------
__global__ void k_final(const float* __restrict__ canvas,
                        const float* __restrict__ kern,
                        const float* __restrict__ eps_dark,
                        const float* __restrict__ eps_photon,
                        const float* __restrict__ eps_read,
                        float* __restrict__ out) {
    __shared__ float kk[49];
    __shared__ float tile[14][40];
    int b = blockIdx.z;
    int tx = threadIdx.x, ty = threadIdx.y;
    int t = ty * 32 + tx;
    int j0 = blockIdx.x * 32, i0 = blockIdx.y * 8;
    if (t < 49) kk[t] = kern[t];
    const float* cb = canvas + (size_t)b * (CAN * CAN);
    for (int p = t; p < 14 * 38; p += 256) {
        int rr = p / 38, cc = p % 38;
        int gi = i0 + rr - 2, gj = j0 + cc - 2;
        tile[rr][cc] = (gi >= 0 && gi < CAN && gj >= 0 && gj < CAN)
                           ? cb[gi * CAN + gj] : 0.f;
    }
    __syncthreads();
    int i = i0 + ty, j = j0 + tx;
    if (i >= OHW || j >= OHW) return;
    float acc = 0.f;
#pragma unroll
    for (int a = 0; a < 7; ++a)
#pragma unroll
        for (int q = 0; q < 7; ++q)
            acc += tile[ty + a][tx + q] * kk[a * 7 + q];
    int idx = b * (OHW * OHW) + i * OHW + j;
    float sig = acc * 0.9f;
    float dark = 0.005f + eps_dark[idx] * sqrtf(0.005f);
    float total = fmaxf(sig + dark, 0.0f);
    float noisy = total + eps_photon[idx] * sqrtf(fmaxf(total, 1e-12f));
    float elec = noisy + eps_read[idx] * 1.6f;
    float adu = fminf(fmaxf(elec * 2.0f, 0.0f), 65535.0f);
    float v = (adu <= 10.0f) ? 1.0f : fminf(adu, 4.0e9f);
    out[idx] = v / 4.0e9f;
}

// ---------------------------------------------------------------------------
extern "C" void kernel_launch(void* const* d_in, const int* in_sizes, int n_in,
                              void* d_out, int out_size, void* d_ws, size_t ws_size,
                              hipStream_t stream) {
    const float* phase    = (const float*)d_in[0];
    const float* zs       = (const float*)d_in[1];
    const int*   xyz      = (const int*)d_in[2];
    const float* std_u    = (const float*)d_in[3];
    const float* epsd     = (const float*)d_in[4];
    const float* epsp     = (const float*)d_in[5];
    const float* epsr     = (const float*)d_in[6];
    float* out = (float*)d_out;

    char* ws = (char*)d_ws;
    size_t off = 0;
    auto alloc = [&](size_t bytes) {
        off = (off + 255) & ~(size_t)255;
        size_t o = off; off += bytes; return o;
    };
    float2* tw       = (float2*)(ws + alloc((size_t)NN * 8));
    float2* R1T      = (float2*)(ws + alloc((size_t)NN * NN * 8));
    float2* EfT      = (float2*)(ws + alloc((size_t)NN * NN * 8));
    float2* part     = (float2*)(ws + alloc((size_t)NE * PW * NN * 8));
    float*  psf      = (float*) (ws + alloc((size_t)NE * PW * PW * 4));
    float*  psf_sums = (float*) (ws + alloc((size_t)NE * 4));
    float*  kern     = (float*) (ws + alloc((size_t)64 * 4));
    float*  canvas   = (float*) (ws + alloc((size_t)BATCH * CAN * CAN * 4));
    (void)ws_size; (void)n_in; (void)in_sizes; (void)out_size;

    k_setup<<<(SETUP_N + 255) / 256, 256, 0, stream>>>(
        std_u, tw, kern, canvas, psf_sums);
    // fft2: rows (fused field gen, writes transposed) then cols (contiguous)
    k_dft_rows<<<NN, 256, 0, stream>>>(phase, R1T, tw);
    k_dft_cols<<<NN, 256, 0, stream>>>(R1T, EfT, tw);
    // partial inverse transforms for the 31x31 crop, all 64 z-planes
    k_prop_rows<<<dim3(NN, 4), 256, 0, stream>>>(EfT, zs, part);
    k_prop_cols<<<dim3(PW, NE), 256, 0, stream>>>(part, psf, psf_sums);
    k_scatter<<<dim3(NE, BATCH), 256, 0, stream>>>(psf, psf_sums, xyz, canvas);
    k_final<<<dim3((OHW + 31) / 32, (OHW + 7) / 8, BATCH), dim3(32, 8), 0, stream>>>(
        canvas, kern, epsd, epsp, epsr, out);
}

// Round 12
// 194.709 us; speedup vs baseline: 1.0462x; 1.0462x over previous
//
#include <hip/hip_runtime.h>
#include <math.h>

#define NN 500
#define NE 64
#define BATCH 8
#define RR 15
#define PW 31            // 2R+1
#define CAN 200
#define OHW 198
#define TWO_PI_F 6.28318530717958647692f
// k_setup covers canvas (320000) + psf_sums (64) + kern (49).
#define SETUP_N (BATCH * CAN * CAN + NE + 49)

// Fast accurate sincos for |theta| up to ~1200 rad: Cody-Waite 2-term
// reduction + hardware v_sin/v_cos on the reduced |r| <= pi argument.
__device__ __forceinline__ void fast_sincos_red(float theta, float* s, float* c) {
    const float INV2PI = 0.15915494309189535f;
    const float PI2_HI = 6.28318548202514648f;   // f32(2*pi)
    const float PI2_LO = -1.7484556e-7f;         // 2*pi - PI2_HI
    float n = rintf(theta * INV2PI);
    float r = fmaf(n, -PI2_HI, theta);
    r = fmaf(n, -PI2_LO, r);
    *s = __sinf(r);
    *c = __cosf(r);
}

// ---------------------------------------------------------------------------
// K_setup: 500-pt twiddle table, blur-kernel coefficients, canvas+psf_sums
// zero. (kgamma inline in k_prop_rows; field gen in k_dft_rows.)
// ---------------------------------------------------------------------------
__global__ void k_setup(const float* __restrict__ std_u,
                        float2* __restrict__ tw,
                        float* __restrict__ kern,
                        float* __restrict__ canvas,
                        float* __restrict__ psf_sums) {
    int idx = blockIdx.x * blockDim.x + threadIdx.x;
    if (idx < NN) {
        double th = 2.0 * M_PI * (double)idx / (double)NN;
        tw[idx] = make_float2((float)cos(th), (float)sin(th));
    }
    if (idx < BATCH * CAN * CAN) canvas[idx] = 0.f;
    if (idx >= BATCH * CAN * CAN && idx < BATCH * CAN * CAN + NE)
        psf_sums[idx - BATCH * CAN * CAN] = 0.f;
    if (idx >= BATCH * CAN * CAN + NE && idx < SETUP_N) {
        int t = idx - (BATCH * CAN * CAN + NE);
        float stdv = 0.8f + 0.4f * std_u[0];
        float s2 = stdv * stdv;
        int a = t / 7 - 3, b = t % 7 - 3;
        float g = (float)exp(-0.5 * (double)(a * a + b * b));
        kern[t] = (1.0f / (2.0f * (float)M_PI * s2)) * powf(g, 1.0f / s2);
    }
}

// ---------------------------------------------------------------------------
// 500-pt forward DFT via Cooley-Tukey 20x25. Shared stages helper.
// ---------------------------------------------------------------------------
__device__ __forceinline__ void ct_dft_stages(const float2* xs, const float2* tts,
                                              float2* S, int t,
                                              float2* out1, float2* out2, int* kout) {
    if (t < 250) {
        int d = t / 25;
        int b = t % 25;
        float2 st = tts[(25 * d) % NN];
        float wr = 1.f, wi = 0.f;
        float Er = 0.f, Ei = 0.f, Or_ = 0.f, Oi = 0.f;
#pragma unroll
        for (int a = 0; a < 20; a += 2) {
            float2 x0 = xs[25 * a + b];
            Er += x0.x * wr - x0.y * wi;
            Ei += x0.x * wi + x0.y * wr;
            float nr = wr * st.x - wi * st.y;
            float ni = wr * st.y + wi * st.x;
            float2 x1 = xs[25 * (a + 1) + b];
            Or_ += x1.x * nr - x1.y * ni;
            Oi  += x1.x * ni + x1.y * nr;
            wr = nr * st.x - ni * st.y;
            wi = nr * st.y + ni * st.x;
        }
        S[b * 21 + d]      = make_float2(Er + Or_, Ei + Oi);
        S[b * 21 + d + 10] = make_float2(Er - Or_, Ei - Oi);
    }
    __syncthreads();
    if (t < 250) {
        int k = t;
        int d1 = k % 20;
        int d2 = (d1 + 10) % 20;
        float2 s1 = tts[k];
        float wr = 1.f, wi = 0.f;
        float a1r = 0.f, a1i = 0.f, a2r = 0.f, a2i = 0.f;
#pragma unroll
        for (int b = 0; b < 25; ++b) {
            float2 u1 = S[b * 21 + d1];
            float2 u2 = S[b * 21 + d2];
            a1r += u1.x * wr - u1.y * wi;
            a1i += u1.x * wi + u1.y * wr;
            float sgnb = (b & 1) ? -1.f : 1.f;
            float w2r = sgnb * wr, w2i = sgnb * wi;
            a2r += u2.x * w2r - u2.y * w2i;
            a2i += u2.x * w2i + u2.y * w2r;
            float nr = wr * s1.x - wi * s1.y;
            wi = wr * s1.y + wi * s1.x;
            wr = nr;
        }
        *out1 = make_float2(a1r, a1i);
        *out2 = make_float2(a2r, a2i);
        *kout = k;
    }
}

// k_dft_rows: fused pupil-field generation (f32) + row DFT; writes R1T[k][y].
__global__ void k_dft_rows(const float* __restrict__ phase, float2* __restrict__ dst,
                           const float2* __restrict__ tw) {
    __shared__ __align__(16) float2 xs[NN];
    __shared__ float2 tts[NN];
    __shared__ float2 S[25 * 21];
    int line = blockIdx.x;                 // y index i
    int t = threadIdx.x;
    const float INV2SIG = 2.2222222e7f;              // 1/(2*(1.5e-4)^2)
    const float C1M = (float)(M_PI / 5.32e-8);       // pi/(WL*FL)
    float y = (float)(line - 250) * 1e-6f;
    float y2 = y * y;
    const float* prow = phase + (size_t)line * NN;
    for (int n = t; n < NN; n += 256) {
        float x = (float)(n - 250) * 1e-6f;
        float r2 = x * x + y2;
        float inc = __expf(-r2 * INV2SIG);
        float c1 = C1M * r2;
        float b1r = __cosf(c1), b1i = -__sinf(c1);
        float ph = prow[n];
        float sp = __sinf(ph), cp = __cosf(ph);
        float ar = inc * cp, ai = inc * sp;
        xs[n] = make_float2(ar * b1r - ai * b1i, ar * b1i + ai * b1r);
        float2 tt = tw[n];
        tts[n] = make_float2(tt.x, -tt.y);   // forward
    }
    __syncthreads();
    float2 o1, o2; int k;
    ct_dft_stages(xs, tts, S, t, &o1, &o2, &k);
    if (t < 250) {
        dst[(size_t)k * NN + line] = o1;           // R1T[k][y]
        dst[(size_t)(k + 250) * NN + line] = o2;
    }
}

__global__ void k_dft_cols(const float2* __restrict__ src, float2* __restrict__ dst,
                           const float2* __restrict__ tw) {
    __shared__ __align__(16) float2 xs[NN];
    __shared__ float2 tts[NN];
    __shared__ float2 S[25 * 21];
    int line = blockIdx.x;                 // kx
    const float2* s = src + (size_t)line * NN;     // R1T row kx, contiguous
    int t = threadIdx.x;
    for (int n = t; n < NN; n += 256) {
        xs[n] = s[n];
        float2 tt = tw[n];
        tts[n] = make_float2(tt.x, -tt.y);
    }
    __syncthreads();
    float2 o1, o2; int k;
    ct_dft_stages(xs, tts, S, t, &o1, &o2, &k);
    if (t < 250) {
        float2* dp = dst + (size_t)line * NN;      // EfT[kx][*], contiguous
        dp[k] = o1;
        dp[k + 250] = o2;
    }
}

// ---------------------------------------------------------------------------
// B1 v12 = v10 grid (NN,2) [4 passes, all-resident — (NN,4) regressed twice
// via part-write amplification + EfT refetch] + v11's inline kgamma,
// __sinf/__cosf rotator init, register-prefetched EfT row.
//   part[z][r][v] = sum_u EfT[v,u]*e^{i*kg[v,u]*z} * e^{+2pi*i*u*r/500}
// ---------------------------------------------------------------------------
__global__ void __launch_bounds__(256, 5)
k_prop_rows(const float2* __restrict__ EfT,
            const float* __restrict__ zs,
            float2* __restrict__ part) {
    __shared__ __align__(16) float4 Yeo[8][250];   // 32000 B
    int v = blockIdx.x;
    int zhalf = blockIdx.y;     // 0..1
    int t = threadIdx.x;
    int w = t >> 6;             // wave id 0..3 -> z rows 2w, 2w+1
    int lane = t & 63;
    int co = lane >> 3;         // 0..7 : r-quad index
    int vs = lane & 7;          // 0..7 : u-segment
    int r0 = 235 + 4 * co;      // r = r0..r0+3 (co=7,rl=3 -> 266 dummy)

    const float2* erow = EfT + (size_t)v * NN;

    // prefetch EfT row pair + inline kgamma (f64, identical op sequence to
    // the reference: a from u/column, b from v/row)
    float2 eA = make_float2(0.f, 0.f), eB = eA;
    float kgA = 0.f, kgB = 0.f;
    if (t < 250) {
        eA = erow[t];   eB = erow[t + 250];
        double fyv = (double)((v < 250) ? v : v - 500) * 2000.0;
        double b = 5.32e-7 * fyv;
        double aA = 5.32e-7 * ((double)t * 2000.0);          // u = t < 250
        double aB = 5.32e-7 * ((double)(t - 250) * 2000.0);  // u = t+250 -> u-500
        double gA = 1.0 - aA * aA - b * b;
        double gB = 1.0 - aB * aB - b * b;
        gA = (gA > 0.0) ? sqrt(gA) : 0.0;
        gB = (gB > 0.0) ? sqrt(gB) : 0.0;
        const float Kf = (float)(2.0 * M_PI * 1.0 / 5.32e-7);
        kgA = Kf * (float)gA;
        kgB = Kf * (float)gB;
    }

    // rotator init via hw sincos (args in [0, 2pi), ~1e-6 — inside budget)
    float w0r[4], w0i[4], s1r[4], s1i[4], str[4], sti[4];
#pragma unroll
    for (int rl = 0; rl < 4; ++rl) {
        int r = r0 + rl;
        float th0 = (TWO_PI_F / NN) * (float)((2 * vs * r) % NN);
        w0i[rl] = __sinf(th0);  w0r[rl] = __cosf(th0);
        float th1 = (TWO_PI_F / NN) * (float)(r % NN);
        s1i[rl] = __sinf(th1);  s1r[rl] = __cosf(th1);
        float ths = (TWO_PI_F / NN) * (float)((16 * r) % NN);
        sti[rl] = __sinf(ths);  str[rl] = __cosf(ths);
    }

    for (int g = 0; g < 4; ++g) {
        int zbase = zhalf * 32 + g * 8;
        float zv[8];
#pragma unroll
        for (int zi = 0; zi < 8; ++zi) zv[zi] = zs[zbase + zi];
        // modulate + parity fold, all from registers
        if (t < 250) {
#pragma unroll
            for (int zi = 0; zi < 8; ++zi) {
                float sA, cA, sB, cB;
                fast_sincos_red(kgA * zv[zi], &sA, &cA);
                fast_sincos_red(kgB * zv[zi], &sB, &cB);
                float y0r = eA.x * cA - eA.y * sA, y0i = eA.x * sA + eA.y * cA;
                float y1r = eB.x * cB - eB.y * sB, y1i = eB.x * sB + eB.y * cB;
                Yeo[zi][t] = make_float4(y0r + y1r, y0i + y1i,
                                         y0r - y1r, y0i - y1i);
            }
        }
        __syncthreads();

        float wr[4], wi[4];
#pragma unroll
        for (int rl = 0; rl < 4; ++rl) { wr[rl] = w0r[rl]; wi[rl] = w0i[rl]; }
        float accr[4][2], acci[4][2];
#pragma unroll
        for (int rl = 0; rl < 4; ++rl)
#pragma unroll
            for (int j = 0; j < 2; ++j) { accr[rl][j] = 0.f; acci[rl][j] = 0.f; }

        for (int pc = vs; pc < 125; pc += 8) {   // columns u=2pc, 2pc+1
            int u = 2 * pc;
            float4 y0a = Yeo[2 * w + 0][u];      // z row 0: col u  {e,o}
            float4 y0b = Yeo[2 * w + 0][u + 1];  // z row 0: col u+1
            float4 y1a = Yeo[2 * w + 1][u];
            float4 y1b = Yeo[2 * w + 1][u + 1];
#pragma unroll
            for (int rl = 0; rl < 4; ++rl) {
                float ar = wr[rl], ai = wi[rl];              // twiddle at u
                float br = ar * s1r[rl] - ai * s1i[rl];      // twiddle at u+1
                float bi = ar * s1i[rl] + ai * s1r[rl];
                if ((rl & 1) == 0) {   // r odd -> odd-parity (.z,.w)
                    accr[rl][0] += y0a.z * ar - y0a.w * ai + y0b.z * br - y0b.w * bi;
                    acci[rl][0] += y0a.z * ai + y0a.w * ar + y0b.z * bi + y0b.w * br;
                    accr[rl][1] += y1a.z * ar - y1a.w * ai + y1b.z * br - y1b.w * bi;
                    acci[rl][1] += y1a.z * ai + y1a.w * ar + y1b.z * bi + y1b.w * br;
                } else {               // r even -> even-parity (.x,.y)
                    accr[rl][0] += y0a.x * ar - y0a.y * ai + y0b.x * br - y0b.y * bi;
                    acci[rl][0] += y0a.x * ai + y0a.y * ar + y0b.x * bi + y0b.y * br;
                    accr[rl][1] += y1a.x * ar - y1a.y * ai + y1b.x * br - y1b.y * bi;
                    acci[rl][1] += y1a.x * ai + y1a.y * ar + y1b.x * bi + y1b.y * br;
                }
                float nwr = ar * str[rl] - ai * sti[rl];
                wi[rl] = ar * sti[rl] + ai * str[rl];
                wr[rl] = nwr;
            }
        }

#pragma unroll
        for (int rl = 0; rl < 4; ++rl)
#pragma unroll
            for (int j = 0; j < 2; ++j) {
#pragma unroll
                for (int m = 1; m < 8; m <<= 1) {
                    accr[rl][j] += __shfl_xor(accr[rl][j], m);
                    acci[rl][j] += __shfl_xor(acci[rl][j], m);
                }
            }
        if (vs == 0) {
#pragma unroll
            for (int rl = 0; rl < 4; ++rl) {
                int r = r0 + rl;
                if (r <= 265) {
#pragma unroll
                    for (int j = 0; j < 2; ++j) {
                        int z = zbase + 2 * w + j;
                        part[((size_t)z * PW + (r - 235)) * NN + v] =
                            make_float2(accr[rl][j], acci[rl][j]);
                    }
                }
            }
        }
        __syncthreads();
    }
}

// ---------------------------------------------------------------------------
// B2 v2: parity fold halves the inner loop:
//   sum_v X[v] W^{vc} = sum_{v<250} (X[v] + (-1)^c X[v+250]) W^{vc}
// ---------------------------------------------------------------------------
__global__ void k_prop_cols(const float2* __restrict__ part,
                            float* __restrict__ psf,
                            float* __restrict__ psf_sums) {
    __shared__ float2 X[NN];
    __shared__ float sred[PW];
    int r = blockIdx.x;    // 31
    int z = blockIdx.y;    // 64
    int t = threadIdx.x;
    const float2* col = part + ((size_t)z * PW + r) * NN;
    for (int v = t; v < NN; v += 256) X[v] = col[v];
    __syncthreads();
    if (t < PW * 8) {
        int ci = t >> 3, seg = t & 7;
        int c = 235 + ci;
        float sign = (c & 1) ? -1.f : 1.f;     // W^{250c} = (-1)^c
        float wr, wi, sr, si;
        {
            float th0 = (TWO_PI_F / NN) * (float)((seg * c) % NN);
            sincosf(th0, &wi, &wr);
            float ths = (TWO_PI_F / NN) * (float)((8 * c) % NN);
            sincosf(ths, &si, &sr);
        }
        float ar = 0.f, ai = 0.f;
        for (int v = seg; v < 250; v += 8) {
            float2 xa = X[v];
            float2 xb = X[v + 250];
            float xr = fmaf(sign, xb.x, xa.x);
            float xi = fmaf(sign, xb.y, xa.y);
            ar += xr * wr - xi * wi;
            ai += xr * wi + xi * wr;
            float nwr = wr * sr - wi * si;
            wi = wr * si + wi * sr;
            wr = nwr;
        }
#pragma unroll
        for (int m = 1; m < 8; m <<= 1) {
            ar += __shfl_xor(ar, m);
            ai += __shfl_xor(ai, m);
        }
        if (seg == 0 && ci < PW) {
            const float inv = 1.0f / 250000.0f;
            float re = ar * inv, im = ai * inv;
            float val = re * re + im * im;
            psf[(size_t)z * (PW * PW) + r * PW + ci] = val;
            sred[ci] = val;
        }
    }
    __syncthreads();
    if (t == 0) {
        float s = 0.f;
#pragma unroll
        for (int i = 0; i < PW; ++i) s += sred[i];
        atomicAdd(&psf_sums[z], s);
    }
}

// ---------------------------------------------------------------------------
__global__ void k_scatter(const float* __restrict__ psf,
                          const float* __restrict__ psf_sums,
                          const int* __restrict__ xyz,
                          float* __restrict__ canvas) {
    int e = blockIdx.x;
    int b = blockIdx.y;
    int r0 = xyz[(b * NE + e) * 2 + 0] - RR;
    int c0 = xyz[(b * NE + e) * 2 + 1] - RR;
    float sc = 1.0e6f / (psf_sums[e] + 1e-12f);
    float* cb = canvas + (size_t)b * (CAN * CAN);
    for (int p = threadIdx.x; p < PW * PW; p += blockDim.x) {
        int i = p / PW, j = p % PW;
        atomicAdd(cb + (r0 + i) * CAN + (c0 + j), psf[e * PW * PW + p] * sc);
    }
}

// ---------------------------------------------------------------------------
__global__ void k_final(const float* __restrict__ canvas,
                        const float* __restrict__ kern,
                        const float* __restrict__ eps_dark,
                        const float* __restrict__ eps_photon,
                        const float* __restrict__ eps_read,
                        float* __restrict__ out) {
    __shared__ float kk[49];
    __shared__ float tile[14][40];
    int b = blockIdx.z;
    int tx = threadIdx.x, ty = threadIdx.y;
    int t = ty * 32 + tx;
    int j0 = blockIdx.x * 32, i0 = blockIdx.y * 8;
    if (t < 49) kk[t] = kern[t];
    const float* cb = canvas + (size_t)b * (CAN * CAN);
    for (int p = t; p < 14 * 38; p += 256) {
        int rr = p / 38, cc = p % 38;
        int gi = i0 + rr - 2, gj = j0 + cc - 2;
        tile[rr][cc] = (gi >= 0 && gi < CAN && gj >= 0 && gj < CAN)
                           ? cb[gi * CAN + gj] : 0.f;
    }
    __syncthreads();
    int i = i0 + ty, j = j0 + tx;
    if (i >= OHW || j >= OHW) return;
    float acc = 0.f;
#pragma unroll
    for (int a = 0; a < 7; ++a)
#pragma unroll
        for (int q = 0; q < 7; ++q)
            acc += tile[ty + a][tx + q] * kk[a * 7 + q];
    int idx = b * (OHW * OHW) + i * OHW + j;
    float sig = acc * 0.9f;
    float dark = 0.005f + eps_dark[idx] * sqrtf(0.005f);
    float total = fmaxf(sig + dark, 0.0f);
    float noisy = total + eps_photon[idx] * sqrtf(fmaxf(total, 1e-12f));
    float elec = noisy + eps_read[idx] * 1.6f;
    float adu = fminf(fmaxf(elec * 2.0f, 0.0f), 65535.0f);
    float v = (adu <= 10.0f) ? 1.0f : fminf(adu, 4.0e9f);
    out[idx] = v / 4.0e9f;
}

// ---------------------------------------------------------------------------
extern "C" void kernel_launch(void* const* d_in, const int* in_sizes, int n_in,
                              void* d_out, int out_size, void* d_ws, size_t ws_size,
                              hipStream_t stream) {
    const float* phase    = (const float*)d_in[0];
    const float* zs       = (const float*)d_in[1];
    const int*   xyz      = (const int*)d_in[2];
    const float* std_u    = (const float*)d_in[3];
    const float* epsd     = (const float*)d_in[4];
    const float* epsp     = (const float*)d_in[5];
    const float* epsr     = (const float*)d_in[6];
    float* out = (float*)d_out;

    char* ws = (char*)d_ws;
    size_t off = 0;
    auto alloc = [&](size_t bytes) {
        off = (off + 255) & ~(size_t)255;
        size_t o = off; off += bytes; return o;
    };
    float2* tw       = (float2*)(ws + alloc((size_t)NN * 8));
    float2* R1T      = (float2*)(ws + alloc((size_t)NN * NN * 8));
    float2* EfT      = (float2*)(ws + alloc((size_t)NN * NN * 8));
    float2* part     = (float2*)(ws + alloc((size_t)NE * PW * NN * 8));
    float*  psf      = (float*) (ws + alloc((size_t)NE * PW * PW * 4));
    float*  psf_sums = (float*) (ws + alloc((size_t)NE * 4));
    float*  kern     = (float*) (ws + alloc((size_t)64 * 4));
    float*  canvas   = (float*) (ws + alloc((size_t)BATCH * CAN * CAN * 4));
    (void)ws_size; (void)n_in; (void)in_sizes; (void)out_size;

    k_setup<<<(SETUP_N + 255) / 256, 256, 0, stream>>>(
        std_u, tw, kern, canvas, psf_sums);
    // fft2: rows (fused field gen, writes transposed) then cols (contiguous)
    k_dft_rows<<<NN, 256, 0, stream>>>(phase, R1T, tw);
    k_dft_cols<<<NN, 256, 0, stream>>>(R1T, EfT, tw);
    // partial inverse transforms for the 31x31 crop, all 64 z-planes
    k_prop_rows<<<dim3(NN, 2), 256, 0, stream>>>(EfT, zs, part);
    k_prop_cols<<<dim3(PW, NE), 256, 0, stream>>>(part, psf, psf_sums);
    k_scatter<<<dim3(NE, BATCH), 256, 0, stream>>>(psf, psf_sums, xyz, canvas);
    k_final<<<dim3((OHW + 31) / 32, (OHW + 7) / 8, BATCH), dim3(32, 8), 0, stream>>>(
        canvas, kern, epsd, epsp, epsr, out);
}